// Round 1
// baseline (390.015 us; speedup 1.0000x reference)
//
#include <hip/hip_runtime.h>

// B=256, C=3, H=W=256, E=8
// out[b,c,h,w] = bilinear_sample(x[b,c], affine(theta_b, (h,w))), zero padding,
// align_corners=False. theta_b = smp_b * Wt[e] + bt[e], e = tsmp[b],
// smp_b = distr_flags[e]==1 ? nsmp[b] : usmp[b].

__global__ __launch_bounds__(256) void dataug_kernel(
    const float* __restrict__ x,
    const float* __restrict__ usmp,
    const float* __restrict__ nsmp,
    const float* __restrict__ Wt,
    const float* __restrict__ bt,
    const int*   __restrict__ tsmp,
    const int*   __restrict__ distr,
    float* __restrict__ out)
{
    constexpr int H = 256, W = 256, C = 3;
    const int bh = blockIdx.x;
    const int b  = bh >> 8;     // / H
    const int h  = bh & 255;    // % H
    const int w  = threadIdx.x;

    // --- per-batch theta (block-uniform -> scalar loads) ---
    const int e = tsmp[b];
    const float smp = (distr[e] == 1) ? nsmp[b] : usmp[b];
    const float t0 = smp * Wt[e*6 + 0] + bt[e*6 + 0];
    const float t1 = smp * Wt[e*6 + 1] + bt[e*6 + 1];
    const float t2 = smp * Wt[e*6 + 2] + bt[e*6 + 2];
    const float t3 = smp * Wt[e*6 + 3] + bt[e*6 + 3];
    const float t4 = smp * Wt[e*6 + 4] + bt[e*6 + 4];
    const float t5 = smp * Wt[e*6 + 5] + bt[e*6 + 5];

    // --- affine grid (align_corners=False) ---
    const float xs = (2.0f * (float)w + 1.0f) / (float)W - 1.0f;
    const float ys = (2.0f * (float)h + 1.0f) / (float)H - 1.0f;
    const float gx = t0 * xs + t1 * ys + t2;
    const float gy = t3 * xs + t4 * ys + t5;

    // --- unnormalize to input pixel space ---
    const float ix = ((gx + 1.0f) * (float)W - 1.0f) * 0.5f;
    const float iy = ((gy + 1.0f) * (float)H - 1.0f) * 0.5f;

    const float ix0f = floorf(ix);
    const float iy0f = floorf(iy);
    const float wx1 = ix - ix0f, wx0 = 1.0f - wx1;
    const float wy1 = iy - iy0f, wy0 = 1.0f - wy1;

    const int ix0 = (int)ix0f, iy0 = (int)iy0f;
    const int ix1 = ix0 + 1,   iy1 = iy0 + 1;

    const bool vx0 = (ix0 >= 0) & (ix0 <= W - 1);
    const bool vx1 = (ix1 >= 0) & (ix1 <= W - 1);
    const bool vy0 = (iy0 >= 0) & (iy0 <= H - 1);
    const bool vy1 = (iy1 >= 0) & (iy1 <= H - 1);

    const int cx0 = min(max(ix0, 0), W - 1);
    const int cx1 = min(max(ix1, 0), W - 1);
    const int cy0 = min(max(iy0, 0), H - 1);
    const int cy1 = min(max(iy1, 0), H - 1);

    // fold validity into weights (equivalent to zeroing invalid taps)
    const float w00 = (vy0 && vx0) ? wy0 * wx0 : 0.0f;
    const float w01 = (vy0 && vx1) ? wy0 * wx1 : 0.0f;
    const float w10 = (vy1 && vx0) ? wy1 * wx0 : 0.0f;
    const float w11 = (vy1 && vx1) ? wy1 * wx1 : 0.0f;

    const int o00 = cy0 * W + cx0;
    const int o01 = cy0 * W + cx1;
    const int o10 = cy1 * W + cx0;
    const int o11 = cy1 * W + cx1;

    const size_t plane = (size_t)H * W;
    const float* img = x   + (size_t)b * C * plane;
    float*       og  = out + (size_t)b * C * plane + (size_t)h * W + w;

#pragma unroll
    for (int c = 0; c < C; ++c) {
        const float* p = img + (size_t)c * plane;
        float v = p[o00] * w00 + p[o01] * w01 + p[o10] * w10 + p[o11] * w11;
        og[c * plane] = v;
    }
}

extern "C" void kernel_launch(void* const* d_in, const int* in_sizes, int n_in,
                              void* d_out, int out_size, void* d_ws, size_t ws_size,
                              hipStream_t stream)
{
    const float* x     = (const float*)d_in[0];
    const float* usmp  = (const float*)d_in[1];
    const float* nsmp  = (const float*)d_in[2];
    const float* Wt    = (const float*)d_in[3];
    const float* bt    = (const float*)d_in[4];
    const int*   tsmp  = (const int*)d_in[5];
    const int*   distr = (const int*)d_in[6];
    float* out = (float*)d_out;

    // B*H blocks of W threads
    dim3 grid(256 * 256);
    dim3 block(256);
    dataug_kernel<<<grid, block, 0, stream>>>(x, usmp, nsmp, Wt, bt, tsmp, distr, out);
}